// Round 7
// baseline (71.732 us; speedup 1.0000x reference)
//
#include <hip/hip_runtime.h>

#define NHEADS 16
#define HDIM   64
#define NFEAT  32
#define PDIM   16
#define NQUAD  2
#define GB     16      // b's per block
#define NTHREADS 1024  // 16 waves; wave w owns h=w

typedef float f32x4 __attribute__((ext_vector_type(4)));

// out[b, r, h, p, m] flat = b*16384 + r*8192 + h*512 + p*32 + m
__global__ __launch_bounds__(NTHREADS, 4)
void slay_kernel(const float* __restrict__ x,
                 const float* __restrict__ omega,
                 const float* __restrict__ anchors,
                 const float* __restrict__ qn,
                 const float* __restrict__ qw,
                 float* __restrict__ out)
{
    // double-buffered feature slab (producer: 16 waves, consumer: whole block)
    __shared__ __align__(16) float s_prf [2][NHEADS][64];    // [h][r*32+m]
    __shared__ __align__(16) float s_poly[2][NHEADS][PDIM];  // [h][p]
    __shared__ __align__(16) float s_xn  [NHEADS][64];       // wave-local staging

    const int tid  = threadIdx.x;
    const int w    = tid >> 6;     // wave index == h
    const int lane = tid & 63;
    const int h    = w;

    const int r = lane >> 5;   // quadrature node
    const int m = lane & 31;   // feature index
    const int p = lane & 15;   // poly index (4x redundant)
    const int g = lane >> 4;   // d-group for poly partial dot

    const float sR     = fmaxf(qn[r], 1e-6f);
    const float sq2s   = sqrtf(2.0f * sR);
    const float scaleR = sqrtf(fmaxf(qw[r], 1e-6f)) / sqrtf(32.0f + 1e-6f);

    // omega column in registers: om[d] = omega[r][h][d][m]
    float om[64];
    {
        const float* oc = omega + ((size_t)(r * NHEADS + h) * HDIM) * NFEAT + m;
        #pragma unroll
        for (int d = 0; d < 64; ++d) om[d] = oc[(size_t)d * NFEAT];
    }
    // anchors slice: an[dd] = anchors[p][g*16+dd]
    float an[16];
    {
        const float* ac = anchors + p * HDIM + g * 16;
        #pragma unroll
        for (int dd = 0; dd < 16; ++dd) an[dd] = ac[dd];
    }

    const int b0 = blockIdx.x * GB;
    const float* xb = x + (size_t)b0 * (NHEADS * HDIM) + h * HDIM + lane;
    float xcur = xb[0];

    for (int bb = 0; bb < GB; ++bb) {
        const int buf = bb & 1;
        float xnext = 0.f;
        if (bb + 1 < GB) xnext = xb[(size_t)(bb + 1) * (NHEADS * HDIM)];

        // ---- normalize x[b, h, :] (lane = d) ----
        float ss = xcur * xcur;
        #pragma unroll
        for (int off = 32; off > 0; off >>= 1) ss += __shfl_xor(ss, off, 64);
        const float xn = xcur / fmaxf(sqrtf(ss), 1e-4f);

        // stage xn (wave-local buffer; compile-time fences, in-wave DS order)
        __builtin_amdgcn_wave_barrier();
        s_xn[w][lane] = xn;
        __builtin_amdgcn_wave_barrier();

        // ---- prf dot: readlane broadcast, 4 independent chains ----
        float a0 = 0.f, a1 = 0.f, a2 = 0.f, a3 = 0.f;
        #pragma unroll
        for (int d = 0; d < 64; d += 4) {
            const float s0 = __uint_as_float(__builtin_amdgcn_readlane(__float_as_uint(xn), d + 0));
            const float s1 = __uint_as_float(__builtin_amdgcn_readlane(__float_as_uint(xn), d + 1));
            const float s2 = __uint_as_float(__builtin_amdgcn_readlane(__float_as_uint(xn), d + 2));
            const float s3 = __uint_as_float(__builtin_amdgcn_readlane(__float_as_uint(xn), d + 3));
            a0 = fmaf(s0, om[d + 0], a0);
            a1 = fmaf(s1, om[d + 1], a1);
            a2 = fmaf(s2, om[d + 2], a2);
            a3 = fmaf(s3, om[d + 3], a3);
        }
        const float accR = (a0 + a1) + (a2 + a3);

        // ---- poly dot: 16-d slice per lane-group, group-reduce ----
        float p0 = 0.f, p1 = 0.f, p2 = 0.f, p3 = 0.f;
        #pragma unroll
        for (int q4 = 0; q4 < 4; ++q4) {
            const f32x4 xq = *(const f32x4*)&s_xn[w][g * 16 + q4 * 4];
            p0 = fmaf(xq.x, an[q4 * 4 + 0], p0);
            p1 = fmaf(xq.y, an[q4 * 4 + 1], p1);
            p2 = fmaf(xq.z, an[q4 * 4 + 2], p2);
            p3 = fmaf(xq.w, an[q4 * 4 + 3], p3);
        }
        float accP = (p0 + p1) + (p2 + p3);
        accP += __shfl_xor(accP, 16, 64);
        accP += __shfl_xor(accP, 32, 64);

        // ---- epilogues ----
        const float arg  = fminf(fmaxf(accR * sq2s - sR, -20.f), 20.f);
        const float prf  = expf(arg) * scaleR;
        const float pc   = fminf(fmaxf(accP, -1.f), 1.f);
        const float poly = pc * pc * 0.25f;

        // ---- publish features to the block ----
        s_prf[buf][w][lane] = prf;
        if (lane < 16) s_poly[buf][w][lane] = poly;

        // LDS-only barrier: NO vmcnt drain — previous b's stores stay in flight
        asm volatile("s_waitcnt lgkmcnt(0)" ::: "memory");
        __builtin_amdgcn_sched_barrier(0);
        __builtin_amdgcn_s_barrier();

        // ---- fill-like burst: block writes b's 64 KB contiguously ----
        float* ob = out + (size_t)(b0 + bb) * (NQUAD * NHEADS * PDIM * NFEAT);
        #pragma unroll
        for (int round = 0; round < 4; ++round) {
            const int j  = round * 4096 + tid * 4;   // float offset in [0,16384)
            const int rr = j >> 13;
            const int hh = (j >> 9) & 15;
            const int pp = (j >> 5) & 15;
            const int mm = j & 31;
            const float pf = s_poly[buf][hh][pp];
            const f32x4 pr = *(const f32x4*)&s_prf[buf][hh][rr * 32 + mm];
            f32x4 v;
            v.x = pf * pr.x; v.y = pf * pr.y; v.z = pf * pr.z; v.w = pf * pr.w;
            *(f32x4*)(ob + j) = v;
        }
        // no trailing barrier: next compute writes the OTHER buffer; all waves
        // finished reading buf at the next barrier before it is overwritten.
        xcur = xnext;
    }
}

extern "C" void kernel_launch(void* const* d_in, const int* in_sizes, int n_in,
                              void* d_out, int out_size, void* d_ws, size_t ws_size,
                              hipStream_t stream)
{
    const float* x       = (const float*)d_in[0];
    const float* omega   = (const float*)d_in[1];
    const float* anchors = (const float*)d_in[2];
    const float* qn      = (const float*)d_in[3];
    const float* qw      = (const float*)d_in[4];
    float* out = (float*)d_out;

    const int Bsz = in_sizes[0] / (NHEADS * HDIM);   // 4096
    dim3 grid(Bsz / GB);                             // 256 blocks = 1 per CU
    slay_kernel<<<grid, NTHREADS, 0, stream>>>(x, omega, anchors, qn, qw, out);
}